// Round 1
// baseline (454.338 us; speedup 1.0000x reference)
//
#include <hip/hip_runtime.h>

// Workspace layout (float offsets)
#define WS_M      0        // Mt[r*100+p] = (w_lin2 @ w_lin1)^T, 10000 floats
#define WS_K      10000    // K[c][a][b][ci][u][v], 2646 floats
#define WS_BETA   12646    // beta[c][a][b], 18 floats
#define WS_W9     12664    // W9[c][ci][dy][dx], 486 floats
#define WS_BT     13150    // beta_tot[c] (interior combined bias), 2 floats
#define WS_INI    16384    // ini[b][c][h][w], 1,638,400 floats
#define WS_UIT    (16384 + 1638400)      // uiT[bc][p][l], 1,638,400 floats
#define WS_UFT    (16384 + 2*1638400)    // ufT[bc][p][l], 1,638,400 floats

// M[p][r] = sum_q w_lin2[p,q] * w_lin1[q,r]; stored TRANSPOSED: Mt[r*100+p]
__global__ __launch_bounds__(256) void k_prepM(const float* __restrict__ wl1,
                                               const float* __restrict__ wl2,
                                               float* __restrict__ Mt) {
    int idx = blockIdx.x * 256 + threadIdx.x;
    if (idx >= 10000) return;
    int p = idx / 100, r = idx % 100;
    float s = 0.f;
    for (int q = 0; q < 200; ++q)
        s += wl2[p * 200 + q] * wl1[q * 100 + r];
    Mt[r * 100 + p] = s;
}

// Composite conv weights: K, beta, W9, beta_tot. Single block.
__global__ __launch_bounds__(256) void k_prepW(const float* __restrict__ wc1,
                                               const float* __restrict__ bc1,
                                               const float* __restrict__ wc2,
                                               const float* __restrict__ bc2,
                                               float* __restrict__ ws) {
    float* K    = ws + WS_K;
    float* Beta = ws + WS_BETA;
    float* W9   = ws + WS_W9;
    float* Bt   = ws + WS_BT;
    __shared__ float sK[2646];
    __shared__ float sBeta[18];
    int t = threadIdx.x;
    for (int idx = t; idx < 2646; idx += 256) {
        int v = idx % 7; int t1 = idx / 7;
        int u = t1 % 7;  int t2 = t1 / 7;
        int ci = t2 % 3; int t3 = t2 / 3;
        int b = t3 % 3;  int t4 = t3 / 3;
        int a = t4 % 3;  int c = t4 / 3;
        float s = 0.f;
        for (int c64 = 0; c64 < 64; ++c64)
            s += wc2[((c * 64 + c64) * 3 + a) * 3 + b] *
                 wc1[((c64 * 3 + ci) * 7 + u) * 7 + v];
        sK[idx] = s; K[idx] = s;
    }
    if (t < 18) {
        int b = t % 3; int a = (t / 3) % 3; int c = t / 9;
        float s = 0.f;
        for (int c64 = 0; c64 < 64; ++c64)
            s += wc2[((c * 64 + c64) * 3 + a) * 3 + b] * bc1[c64];
        sBeta[t] = s; Beta[t] = s;
    }
    __syncthreads();
    for (int idx = t; idx < 486; idx += 256) {
        int dx = idx % 9; int t1 = idx / 9;
        int dy = t1 % 9;  int t2 = t1 / 9;
        int ci = t2 % 3;  int c = t2 / 3;
        float s = 0.f;
        for (int a = 0; a < 3; ++a) {
            int u = dy - a; if (u < 0 || u > 6) continue;
            for (int b = 0; b < 3; ++b) {
                int v = dx - b; if (v < 0 || v > 6) continue;
                s += sK[((a * 3 + b) * 3 + ci) * 49 + c * 1323 + u * 7 + v];
            }
        }
        W9[idx] = s;  // layout c*243 + ci*81 + dy*9 + dx
    }
    if (t < 2) {
        float s = bc2[t];
        for (int j = 0; j < 9; ++j) s += sBeta[t * 9 + j];
        Bt[t] = s;
    }
}

// ini[b][c][h][w]: interior via 9x9 composite; 1-px border via exact K-decomposition.
__global__ __launch_bounds__(256) void k_conv(const float* __restrict__ x,
                                              const float* __restrict__ bc2,
                                              const float* __restrict__ ws,
                                              float* __restrict__ ini) {
    __shared__ float sW9[486];
    __shared__ float sBt[2];
    for (int i = threadIdx.x; i < 486; i += 256) sW9[i] = ws[WS_W9 + i];
    if (threadIdx.x < 2) sBt[threadIdx.x] = ws[WS_BT + threadIdx.x];
    __syncthreads();
    int tid = blockIdx.x * 256 + threadIdx.x;   // exactly 8*320*320 threads
    int b   = tid / 102400;
    int rem = tid % 102400;
    int h = rem / 320, w = rem % 320;
    float acc0, acc1;
    bool interior = (h >= 1 && h <= 318 && w >= 1 && w <= 318);
    if (interior) {
        acc0 = sBt[0]; acc1 = sBt[1];
        for (int ci = 0; ci < 3; ++ci) {
            const float* xb  = x + (b * 3 + ci) * 102400;
            const float* w0  = sW9 + ci * 81;
            const float* w1p = sW9 + 243 + ci * 81;
            for (int dy = 0; dy < 9; ++dy) {
                int hh = h + dy - 4;
                if ((unsigned)hh >= 320u) continue;
                const float* xr = xb + hh * 320;
                #pragma unroll
                for (int dx = 0; dx < 9; ++dx) {
                    int ww = w + dx - 4;
                    if ((unsigned)ww >= 320u) continue;
                    float xx = xr[ww];
                    acc0 += w0[dy * 9 + dx] * xx;
                    acc1 += w1p[dy * 9 + dx] * xx;
                }
            }
        }
    } else {
        const float* K    = ws + WS_K;
        const float* Beta = ws + WS_BETA;
        acc0 = bc2[0]; acc1 = bc2[1];
        for (int a = 0; a < 3; ++a) {
            int hh0 = h + a - 1;
            if ((unsigned)hh0 >= 320u) continue;
            for (int bb = 0; bb < 3; ++bb) {
                int ww0 = w + bb - 1;
                if ((unsigned)ww0 >= 320u) continue;
                acc0 += Beta[a * 3 + bb];
                acc1 += Beta[9 + a * 3 + bb];
                for (int ci = 0; ci < 3; ++ci) {
                    const float* xb = x + (b * 3 + ci) * 102400;
                    const float* K0 = K + ((a * 3 + bb) * 3 + ci) * 49;
                    const float* K1 = K0 + 1323;
                    for (int u = 0; u < 7; ++u) {
                        int hx = hh0 + u - 3;
                        if ((unsigned)hx >= 320u) continue;
                        for (int v = 0; v < 7; ++v) {
                            int wx = ww0 + v - 3;
                            if ((unsigned)wx >= 320u) continue;
                            float xx = xb[hx * 320 + wx];
                            acc0 += K0[u * 7 + v] * xx;
                            acc1 += K1[u * 7 + v] * xx;
                        }
                    }
                }
            }
        }
    }
    ini[(b * 2 + 0) * 102400 + rem] = acc0;
    ini[(b * 2 + 1) * 102400 + rem] = acc1;
}

// trans: outT[bc][p][l] = relu( sum_r M[p][r] * patchval[bc][l][r] )
// MODE 0: patches from ini (in ws). MODE 1: fea computed on-the-fly from x.
// Block: one bc, 64 patches (lg), 50 p's (pg). Thread tile 2p x 8l (200 active).
template <int MODE>
__global__ __launch_bounds__(256) void k_trans(const float* __restrict__ src,
                                               const float* __restrict__ wfm,
                                               const float* __restrict__ bfm,
                                               const float* __restrict__ ws,
                                               float* __restrict__ outT) {
    __shared__ float sM[100 * 50];   // sM[r*50 + (p - pg*50)]
    __shared__ float sP[100 * 64];   // sP[r*64 + li]
    int bc = blockIdx.x;   // 0..15
    int lg = blockIdx.y;   // 0..15 -> 64 patches each
    int pg = blockIdx.z;   // 0..1  -> 50 p's each
    int t = threadIdx.x;
    const float* Mt = ws + WS_M;
    for (int i = t; i < 5000; i += 256) {
        int r = i / 50, p = i % 50;
        sM[i] = Mt[r * 100 + pg * 50 + p];
    }
    int b = bc >> 1, c = bc & 1;
    int l0 = lg * 64;
    float wf0 = 0.f, wf1 = 0.f, wf2 = 0.f, bf = 0.f;
    if (MODE == 1) { wf0 = wfm[c * 3 + 0]; wf1 = wfm[c * 3 + 1]; wf2 = wfm[c * 3 + 2]; bf = bfm[c]; }
    for (int e = t; e < 6400; e += 256) {
        int r = e / 64, li = e & 63;
        int l = l0 + li;
        int ph = l >> 5, pw = l & 31;
        int row = ph * 10 + r / 10, col = pw * 10 + r % 10;
        float val;
        if (MODE == 0) {
            val = src[bc * 102400 + row * 320 + col];
        } else {
            int off = row * 320 + col;
            val = (bf + src[(b * 3 + 0) * 102400 + off] * wf0
                      + src[(b * 3 + 1) * 102400 + off] * wf1
                      + src[(b * 3 + 2) * 102400 + off] * wf2) * 0.25f;
        }
        sP[r * 64 + li] = val;
    }
    __syncthreads();
    if (t < 200) {
        int py = t / 8;        // 0..24 -> p0 = py*2
        int lx = t % 8;        // lo = lx*8
        int p0 = py * 2, lo = lx * 8;
        float acc[2][8];
        #pragma unroll
        for (int i = 0; i < 2; ++i)
            #pragma unroll
            for (int j = 0; j < 8; ++j) acc[i][j] = 0.f;
        for (int r = 0; r < 100; ++r) {
            float2 a  = *(const float2*)&sM[r * 50 + p0];
            float4 b0 = *(const float4*)&sP[r * 64 + lo];
            float4 b1 = *(const float4*)&sP[r * 64 + lo + 4];
            float av[2] = {a.x, a.y};
            float bv[8] = {b0.x, b0.y, b0.z, b0.w, b1.x, b1.y, b1.z, b1.w};
            #pragma unroll
            for (int i = 0; i < 2; ++i)
                #pragma unroll
                for (int j = 0; j < 8; ++j)
                    acc[i][j] += av[i] * bv[j];
        }
        #pragma unroll
        for (int i = 0; i < 2; ++i) {
            int pglob = pg * 50 + p0 + i;
            float* o = outT + (bc * 100 + pglob) * 1024 + l0 + lo;
            float4 v0 = make_float4(fmaxf(acc[i][0], 0.f), fmaxf(acc[i][1], 0.f),
                                    fmaxf(acc[i][2], 0.f), fmaxf(acc[i][3], 0.f));
            float4 v1 = make_float4(fmaxf(acc[i][4], 0.f), fmaxf(acc[i][5], 0.f),
                                    fmaxf(acc[i][6], 0.f), fmaxf(acc[i][7], 0.f));
            *(float4*)&o[0] = v0;
            *(float4*)&o[4] = v1;
        }
    }
}

// att[bc][l][m] = sum_p uiT[bc][p][l] * ufT[bc][p][m] * 0.01
// Block: 64x64 tile, 256 threads, 4x4 per thread.
__global__ __launch_bounds__(256) void k_att(const float* __restrict__ uiT,
                                             const float* __restrict__ ufT,
                                             float* __restrict__ out) {
    __shared__ float su[100 * 64];
    __shared__ float sv[100 * 64];
    int bc   = blockIdx.z;
    int row0 = blockIdx.y * 64;
    int col0 = blockIdx.x * 64;
    int t = threadIdx.x;
    const float* ubase = uiT + bc * 102400;
    const float* vbase = ufT + bc * 102400;
    for (int e = t; e < 6400; e += 256) {
        int k = e >> 6, r = e & 63;
        su[e] = ubase[k * 1024 + row0 + r];
        sv[e] = vbase[k * 1024 + col0 + r];
    }
    __syncthreads();
    int tx = t & 15, ty = t >> 4;
    float acc[4][4];
    #pragma unroll
    for (int i = 0; i < 4; ++i)
        #pragma unroll
        for (int j = 0; j < 4; ++j) acc[i][j] = 0.f;
    for (int k = 0; k < 100; ++k) {
        float4 a  = *(const float4*)&su[k * 64 + ty * 4];
        float4 bv = *(const float4*)&sv[k * 64 + tx * 4];
        float av[4] = {a.x, a.y, a.z, a.w};
        float bb[4] = {bv.x, bv.y, bv.z, bv.w};
        #pragma unroll
        for (int i = 0; i < 4; ++i)
            #pragma unroll
            for (int j = 0; j < 4; ++j)
                acc[i][j] += av[i] * bb[j];
    }
    float* obase = out + ((size_t)(bc * 1024 + row0)) * 1024 + col0;
    #pragma unroll
    for (int i = 0; i < 4; ++i) {
        int row = ty * 4 + i;
        float4 v = make_float4(acc[i][0] * 0.01f, acc[i][1] * 0.01f,
                               acc[i][2] * 0.01f, acc[i][3] * 0.01f);
        *(float4*)&obase[row * 1024 + tx * 4] = v;
    }
}

extern "C" void kernel_launch(void* const* d_in, const int* in_sizes, int n_in,
                              void* d_out, int out_size, void* d_ws, size_t ws_size,
                              hipStream_t stream) {
    const float* x       = (const float*)d_in[0];
    const float* w_conv1 = (const float*)d_in[1];
    const float* b_conv1 = (const float*)d_in[2];
    const float* w_conv2 = (const float*)d_in[3];
    const float* b_conv2 = (const float*)d_in[4];
    const float* w_fm    = (const float*)d_in[5];
    const float* b_fm    = (const float*)d_in[6];
    const float* w_lin1  = (const float*)d_in[7];
    const float* w_lin2  = (const float*)d_in[8];
    float* out = (float*)d_out;
    float* ws  = (float*)d_ws;

    k_prepM<<<40, 256, 0, stream>>>(w_lin1, w_lin2, ws + WS_M);
    k_prepW<<<1, 256, 0, stream>>>(w_conv1, b_conv1, w_conv2, b_conv2, ws);
    k_conv<<<3200, 256, 0, stream>>>(x, b_conv2, ws, ws + WS_INI);
    dim3 gt(16, 16, 2);
    k_trans<0><<<gt, 256, 0, stream>>>(ws + WS_INI, w_fm, b_fm, ws, ws + WS_UIT);
    k_trans<1><<<gt, 256, 0, stream>>>(x, w_fm, b_fm, ws, ws + WS_UFT);
    dim3 ga(16, 16, 16);
    k_att<<<ga, 256, 0, stream>>>(ws + WS_UIT, ws + WS_UFT, out);
}

// Round 2
// 404.167 us; speedup vs baseline: 1.1241x; 1.1241x over previous
//
#include <hip/hip_runtime.h>

// Workspace layout (float offsets)
#define WS_M      0        // Mt[r*100+p] = (w_lin2 @ w_lin1)^T, 10000 floats
#define WS_K      10000    // K[c][a][b][ci][u][v], 2646 floats
#define WS_BETA   12646    // beta[c][a][b], 18 floats
#define WS_W9     12664    // W9[c][ci][dy][dx], 486 floats
#define WS_BT     13150    // beta_tot[c] (interior combined bias), 2 floats
#define WS_INI    16384    // ini[b][c][h][w], 1,638,400 floats
#define WS_UIT    (16384 + 1638400)      // uiT[bc][p][l], 1,638,400 floats
#define WS_UFT    (16384 + 2*1638400)    // ufT[bc][p][l], 1,638,400 floats

// M[p][r] = sum_q w_lin2[p,q] * w_lin1[q,r]; stored TRANSPOSED: Mt[r*100+p]
__global__ __launch_bounds__(256) void k_prepM(const float* __restrict__ wl1,
                                               const float* __restrict__ wl2,
                                               float* __restrict__ Mt) {
    int idx = blockIdx.x * 256 + threadIdx.x;
    if (idx >= 10000) return;
    int p = idx / 100, r = idx % 100;
    float s = 0.f;
    for (int q = 0; q < 200; ++q)
        s += wl2[p * 200 + q] * wl1[q * 100 + r];
    Mt[r * 100 + p] = s;
}

// Composite conv weights: K, beta, W9, beta_tot. Single block.
__global__ __launch_bounds__(256) void k_prepW(const float* __restrict__ wc1,
                                               const float* __restrict__ bc1,
                                               const float* __restrict__ wc2,
                                               const float* __restrict__ bc2,
                                               float* __restrict__ ws) {
    float* K    = ws + WS_K;
    float* Beta = ws + WS_BETA;
    float* W9   = ws + WS_W9;
    float* Bt   = ws + WS_BT;
    __shared__ float sK[2646];
    __shared__ float sBeta[18];
    int t = threadIdx.x;
    for (int idx = t; idx < 2646; idx += 256) {
        int v = idx % 7; int t1 = idx / 7;
        int u = t1 % 7;  int t2 = t1 / 7;
        int ci = t2 % 3; int t3 = t2 / 3;
        int b = t3 % 3;  int t4 = t3 / 3;
        int a = t4 % 3;  int c = t4 / 3;
        float s = 0.f;
        for (int c64 = 0; c64 < 64; ++c64)
            s += wc2[((c * 64 + c64) * 3 + a) * 3 + b] *
                 wc1[((c64 * 3 + ci) * 7 + u) * 7 + v];
        sK[idx] = s; K[idx] = s;
    }
    if (t < 18) {
        int b = t % 3; int a = (t / 3) % 3; int c = t / 9;
        float s = 0.f;
        for (int c64 = 0; c64 < 64; ++c64)
            s += wc2[((c * 64 + c64) * 3 + a) * 3 + b] * bc1[c64];
        sBeta[t] = s; Beta[t] = s;
    }
    __syncthreads();
    for (int idx = t; idx < 486; idx += 256) {
        int dx = idx % 9; int t1 = idx / 9;
        int dy = t1 % 9;  int t2 = t1 / 9;
        int ci = t2 % 3;  int c = t2 / 3;
        float s = 0.f;
        for (int a = 0; a < 3; ++a) {
            int u = dy - a; if (u < 0 || u > 6) continue;
            for (int b = 0; b < 3; ++b) {
                int v = dx - b; if (v < 0 || v > 6) continue;
                s += sK[((a * 3 + b) * 3 + ci) * 49 + c * 1323 + u * 7 + v];
            }
        }
        W9[idx] = s;  // layout c*243 + ci*81 + dy*9 + dx
    }
    if (t < 2) {
        float s = bc2[t];
        for (int j = 0; j < 9; ++j) s += sBeta[t * 9 + j];
        Bt[t] = s;
    }
}

// ini[b][c][h][w]: LDS-tiled. 32x32 output tile/block; input tile 40x40x3 in LDS
// (col stride 48 -> 4-way instead of 8-way b128 bank conflicts).
// Interior: 9x9 composite, weights via wave-uniform global reads (s_load).
// Border (1px frame): exact K-decomposition, reading the same LDS tile.
__global__ __launch_bounds__(256) void k_conv(const float* __restrict__ x,
                                              const float* __restrict__ bc2,
                                              const float* __restrict__ ws,
                                              float* __restrict__ ini) {
    __shared__ float sx[3][40][48];
    int b   = blockIdx.z;
    int gh0 = blockIdx.y * 32, gw0 = blockIdx.x * 32;
    int t = threadIdx.x;
    for (int idx = t; idx < 3 * 40 * 40; idx += 256) {
        int ci = idx / 1600;
        int rem = idx - ci * 1600;
        int rr = rem / 40, cc = rem - rr * 40;
        int gh = gh0 - 4 + rr, gw = gw0 - 4 + cc;
        float v = 0.f;
        if ((unsigned)gh < 320u && (unsigned)gw < 320u)
            v = x[(b * 3 + ci) * 102400 + gh * 320 + gw];
        sx[ci][rr][cc] = v;
    }
    __syncthreads();
    const float* W9g = ws + WS_W9;   // wave-uniform addresses -> SGPR loads
    const float* Btg = ws + WS_BT;
    int r = t >> 3, cg = t & 7;
    int h = gh0 + r, w0c = gw0 + cg * 4;
    float acc0[4], acc1[4];
    float bt0 = Btg[0], bt1 = Btg[1];
    #pragma unroll
    for (int j = 0; j < 4; ++j) { acc0[j] = bt0; acc1[j] = bt1; }
    #pragma unroll
    for (int ci = 0; ci < 3; ++ci) {
        #pragma unroll
        for (int dy = 0; dy < 9; ++dy) {
            const float* xr = &sx[ci][r + dy][cg * 4];
            float4 xa = *(const float4*)(xr);
            float4 xb = *(const float4*)(xr + 4);
            float4 xc = *(const float4*)(xr + 8);
            float xv[12] = {xa.x, xa.y, xa.z, xa.w,
                            xb.x, xb.y, xb.z, xb.w,
                            xc.x, xc.y, xc.z, xc.w};
            #pragma unroll
            for (int dx = 0; dx < 9; ++dx) {
                float w0t = W9g[ci * 81 + dy * 9 + dx];
                float w1t = W9g[243 + ci * 81 + dy * 9 + dx];
                #pragma unroll
                for (int j = 0; j < 4; ++j) {
                    acc0[j] += w0t * xv[dx + j];
                    acc1[j] += w1t * xv[dx + j];
                }
            }
        }
    }
    // Border fix-up: exact per-(a,b)-tap decomposition (valid intermediate taps only)
    bool rowB = (h == 0) | (h == 319);
    if (rowB | (w0c == 0) | (w0c + 3 == 319)) {
        const float* Kg = ws + WS_K;
        const float* Bg = ws + WS_BETA;
        #pragma unroll
        for (int j = 0; j < 4; ++j) {
            int w = w0c + j;
            if (!(rowB | (w == 0) | (w == 319))) continue;
            float a0 = bc2[0], a1 = bc2[1];
            #pragma unroll 1
            for (int a = 0; a < 3; ++a) {
                int hh0 = h + a - 1;
                if ((unsigned)hh0 >= 320u) continue;
                #pragma unroll 1
                for (int bb = 0; bb < 3; ++bb) {
                    int ww0 = w + bb - 1;
                    if ((unsigned)ww0 >= 320u) continue;
                    a0 += Bg[a * 3 + bb];
                    a1 += Bg[9 + a * 3 + bb];
                    #pragma unroll 1
                    for (int ci = 0; ci < 3; ++ci) {
                        const float* K0 = Kg + ((a * 3 + bb) * 3 + ci) * 49;
                        const float* K1 = K0 + 1323;
                        #pragma unroll 1
                        for (int u = 0; u < 7; ++u) {
                            int hx = hh0 + u - 3;
                            if ((unsigned)hx >= 320u) continue;
                            int lh = hx - gh0 + 4;
                            for (int v = 0; v < 7; ++v) {
                                int wx = ww0 + v - 3;
                                if ((unsigned)wx >= 320u) continue;
                                int lw = wx - gw0 + 4;
                                float xx = sx[ci][lh][lw];
                                a0 += K0[u * 7 + v] * xx;
                                a1 += K1[u * 7 + v] * xx;
                            }
                        }
                    }
                }
            }
            acc0[j] = a0; acc1[j] = a1;
        }
    }
    size_t obase = (size_t)(b * 2) * 102400 + h * 320 + w0c;
    *(float4*)&ini[obase] = make_float4(acc0[0], acc0[1], acc0[2], acc0[3]);
    *(float4*)&ini[obase + 102400] = make_float4(acc1[0], acc1[1], acc1[2], acc1[3]);
}

// trans: outT[bc][p][l] = relu( sum_r M[p][r] * patchval[bc][l][r] )
// MODE 0: patches from ini (in ws). MODE 1: fea computed on-the-fly from x.
template <int MODE>
__global__ __launch_bounds__(256) void k_trans(const float* __restrict__ src,
                                               const float* __restrict__ wfm,
                                               const float* __restrict__ bfm,
                                               const float* __restrict__ ws,
                                               float* __restrict__ outT) {
    __shared__ float sM[100 * 50];   // sM[r*50 + (p - pg*50)]
    __shared__ float sP[100 * 64];   // sP[r*64 + li]
    int bc = blockIdx.x;   // 0..15
    int lg = blockIdx.y;   // 0..15 -> 64 patches each
    int pg = blockIdx.z;   // 0..1  -> 50 p's each
    int t = threadIdx.x;
    const float* Mt = ws + WS_M;
    for (int i = t; i < 5000; i += 256) {
        int r = i / 50, p = i % 50;
        sM[i] = Mt[r * 100 + pg * 50 + p];
    }
    int b = bc >> 1, c = bc & 1;
    int l0 = lg * 64;
    float wf0 = 0.f, wf1 = 0.f, wf2 = 0.f, bf = 0.f;
    if (MODE == 1) { wf0 = wfm[c * 3 + 0]; wf1 = wfm[c * 3 + 1]; wf2 = wfm[c * 3 + 2]; bf = bfm[c]; }
    for (int e = t; e < 6400; e += 256) {
        int r = e / 64, li = e & 63;
        int l = l0 + li;
        int ph = l >> 5, pw = l & 31;
        int row = ph * 10 + r / 10, col = pw * 10 + r % 10;
        float val;
        if (MODE == 0) {
            val = src[bc * 102400 + row * 320 + col];
        } else {
            int off = row * 320 + col;
            val = (bf + src[(b * 3 + 0) * 102400 + off] * wf0
                      + src[(b * 3 + 1) * 102400 + off] * wf1
                      + src[(b * 3 + 2) * 102400 + off] * wf2) * 0.25f;
        }
        sP[r * 64 + li] = val;
    }
    __syncthreads();
    if (t < 200) {
        int py = t / 8;        // 0..24 -> p0 = py*2
        int lx = t % 8;        // lo = lx*8
        int p0 = py * 2, lo = lx * 8;
        float acc[2][8];
        #pragma unroll
        for (int i = 0; i < 2; ++i)
            #pragma unroll
            for (int j = 0; j < 8; ++j) acc[i][j] = 0.f;
        for (int r = 0; r < 100; ++r) {
            float2 a  = *(const float2*)&sM[r * 50 + p0];
            float4 b0 = *(const float4*)&sP[r * 64 + lo];
            float4 b1 = *(const float4*)&sP[r * 64 + lo + 4];
            float av[2] = {a.x, a.y};
            float bv[8] = {b0.x, b0.y, b0.z, b0.w, b1.x, b1.y, b1.z, b1.w};
            #pragma unroll
            for (int i = 0; i < 2; ++i)
                #pragma unroll
                for (int j = 0; j < 8; ++j)
                    acc[i][j] += av[i] * bv[j];
        }
        #pragma unroll
        for (int i = 0; i < 2; ++i) {
            int pglob = pg * 50 + p0 + i;
            float* o = outT + (bc * 100 + pglob) * 1024 + l0 + lo;
            float4 v0 = make_float4(fmaxf(acc[i][0], 0.f), fmaxf(acc[i][1], 0.f),
                                    fmaxf(acc[i][2], 0.f), fmaxf(acc[i][3], 0.f));
            float4 v1 = make_float4(fmaxf(acc[i][4], 0.f), fmaxf(acc[i][5], 0.f),
                                    fmaxf(acc[i][6], 0.f), fmaxf(acc[i][7], 0.f));
            *(float4*)&o[0] = v0;
            *(float4*)&o[4] = v1;
        }
    }
}

// att[bc][l][m] = sum_p uiT[bc][p][l] * ufT[bc][p][m] * 0.01
// 128x128 tile, 256 threads, 8x8 per thread, k-chunked LDS (20x128 x2).
#define AKC 20
__global__ __launch_bounds__(256) void k_att(const float* __restrict__ uiT,
                                             const float* __restrict__ ufT,
                                             float* __restrict__ out) {
    __shared__ float su[AKC][128];
    __shared__ float sv[AKC][128];
    int bc   = blockIdx.z;
    int row0 = blockIdx.y * 128;
    int col0 = blockIdx.x * 128;
    int t = threadIdx.x;
    int tx = t & 15, ty = t >> 4;
    const float* ub = uiT + bc * 102400;
    const float* vb = ufT + bc * 102400;
    float acc[8][8];
    #pragma unroll
    for (int i = 0; i < 8; ++i)
        #pragma unroll
        for (int j = 0; j < 8; ++j) acc[i][j] = 0.f;
    for (int k0 = 0; k0 < 100; k0 += AKC) {
        for (int e = t; e < AKC * 128; e += 256) {
            int kk = e >> 7, cc = e & 127;
            su[kk][cc] = ub[(k0 + kk) * 1024 + row0 + cc];
            sv[kk][cc] = vb[(k0 + kk) * 1024 + col0 + cc];
        }
        __syncthreads();
        #pragma unroll
        for (int kk = 0; kk < AKC; ++kk) {
            float4 a0 = *(const float4*)&su[kk][ty * 8];
            float4 a1 = *(const float4*)&su[kk][ty * 8 + 4];
            float4 b0 = *(const float4*)&sv[kk][tx * 8];
            float4 b1 = *(const float4*)&sv[kk][tx * 8 + 4];
            float av[8] = {a0.x, a0.y, a0.z, a0.w, a1.x, a1.y, a1.z, a1.w};
            float bv[8] = {b0.x, b0.y, b0.z, b0.w, b1.x, b1.y, b1.z, b1.w};
            #pragma unroll
            for (int i = 0; i < 8; ++i)
                #pragma unroll
                for (int j = 0; j < 8; ++j)
                    acc[i][j] += av[i] * bv[j];
        }
        __syncthreads();
    }
    #pragma unroll
    for (int i = 0; i < 8; ++i) {
        float* o = out + ((size_t)(bc * 1024 + row0 + ty * 8 + i)) * 1024 + col0 + tx * 8;
        float4 v0 = make_float4(acc[i][0] * 0.01f, acc[i][1] * 0.01f,
                                acc[i][2] * 0.01f, acc[i][3] * 0.01f);
        float4 v1 = make_float4(acc[i][4] * 0.01f, acc[i][5] * 0.01f,
                                acc[i][6] * 0.01f, acc[i][7] * 0.01f);
        *(float4*)&o[0] = v0;
        *(float4*)&o[4] = v1;
    }
}

extern "C" void kernel_launch(void* const* d_in, const int* in_sizes, int n_in,
                              void* d_out, int out_size, void* d_ws, size_t ws_size,
                              hipStream_t stream) {
    const float* x       = (const float*)d_in[0];
    const float* w_conv1 = (const float*)d_in[1];
    const float* b_conv1 = (const float*)d_in[2];
    const float* w_conv2 = (const float*)d_in[3];
    const float* b_conv2 = (const float*)d_in[4];
    const float* w_fm    = (const float*)d_in[5];
    const float* b_fm    = (const float*)d_in[6];
    const float* w_lin1  = (const float*)d_in[7];
    const float* w_lin2  = (const float*)d_in[8];
    float* out = (float*)d_out;
    float* ws  = (float*)d_ws;

    k_prepM<<<40, 256, 0, stream>>>(w_lin1, w_lin2, ws + WS_M);
    k_prepW<<<1, 256, 0, stream>>>(w_conv1, b_conv1, w_conv2, b_conv2, ws);
    k_conv<<<dim3(10, 10, 8), 256, 0, stream>>>(x, b_conv2, ws, ws + WS_INI);
    dim3 gt(16, 16, 2);
    k_trans<0><<<gt, 256, 0, stream>>>(ws + WS_INI, w_fm, b_fm, ws, ws + WS_UIT);
    k_trans<1><<<gt, 256, 0, stream>>>(x, w_fm, b_fm, ws, ws + WS_UFT);
    dim3 ga(8, 8, 16);
    k_att<<<ga, 256, 0, stream>>>(ws + WS_UIT, ws + WS_UFT, out);
}

// Round 3
// 350.320 us; speedup vs baseline: 1.2969x; 1.1537x over previous
//
#include <hip/hip_runtime.h>

// Workspace layout (float offsets)
#define WS_M      0        // Mt[r*100+p] = (w_lin2 @ w_lin1)^T, 10000 floats
#define WS_K      10000    // K[c][a][b][ci][u][v], 2646 floats
#define WS_BETA   12646    // beta[c][a][b], 18 floats
#define WS_W9     12664    // W9[c][ci][dy][dx], 486 floats
#define WS_BT     13150    // beta_tot[c] (interior combined bias), 2 floats
#define WS_INI    16384    // ini[b][c][h][w], 1,638,400 floats
#define WS_UIT    (16384 + 1638400)      // uiT[bc][p][l], 1,638,400 floats
#define WS_UFT    (16384 + 2*1638400)    // ufT[bc][p][l], 1,638,400 floats

// M[p][r] = sum_q w_lin2[p,q] * w_lin1[q,r]; stored TRANSPOSED: Mt[r*100+p]
__global__ __launch_bounds__(256) void k_prepM(const float* __restrict__ wl1,
                                               const float* __restrict__ wl2,
                                               float* __restrict__ Mt) {
    int idx = blockIdx.x * 256 + threadIdx.x;
    if (idx >= 10000) return;
    int p = idx / 100, r = idx % 100;
    float s = 0.f;
    for (int q = 0; q < 200; ++q)
        s += wl2[p * 200 + q] * wl1[q * 100 + r];
    Mt[r * 100 + p] = s;
}

// Composite conv weights: K, beta, W9, beta_tot. Single block; weights staged in LDS.
__global__ __launch_bounds__(256) void k_prepW(const float* __restrict__ wc1,
                                               const float* __restrict__ bc1,
                                               const float* __restrict__ wc2,
                                               const float* __restrict__ bc2,
                                               float* __restrict__ ws) {
    float* K    = ws + WS_K;
    float* Beta = ws + WS_BETA;
    float* W9   = ws + WS_W9;
    float* Bt   = ws + WS_BT;
    __shared__ float swc1[9408];   // 64*3*49
    __shared__ float swc2[1152];   // 2*64*9
    __shared__ float sK[2646];
    __shared__ float sBeta[18];
    int t = threadIdx.x;
    for (int i = t; i < 9408; i += 256) swc1[i] = wc1[i];
    for (int i = t; i < 1152; i += 256) swc2[i] = wc2[i];
    __syncthreads();
    for (int idx = t; idx < 2646; idx += 256) {
        int v = idx % 7; int t1 = idx / 7;
        int u = t1 % 7;  int t2 = t1 / 7;
        int ci = t2 % 3; int t3 = t2 / 3;
        int b = t3 % 3;  int t4 = t3 / 3;
        int a = t4 % 3;  int c = t4 / 3;
        float s = 0.f;
        for (int c64 = 0; c64 < 64; ++c64)
            s += swc2[((c * 64 + c64) * 3 + a) * 3 + b] *
                 swc1[((c64 * 3 + ci) * 7 + u) * 7 + v];
        sK[idx] = s; K[idx] = s;
    }
    if (t < 18) {
        int b = t % 3; int a = (t / 3) % 3; int c = t / 9;
        float s = 0.f;
        for (int c64 = 0; c64 < 64; ++c64)
            s += swc2[((c * 64 + c64) * 3 + a) * 3 + b] * bc1[c64];
        sBeta[t] = s; Beta[t] = s;
    }
    __syncthreads();
    for (int idx = t; idx < 486; idx += 256) {
        int dx = idx % 9; int t1 = idx / 9;
        int dy = t1 % 9;  int t2 = t1 / 9;
        int ci = t2 % 3;  int c = t2 / 3;
        float s = 0.f;
        for (int a = 0; a < 3; ++a) {
            int u = dy - a; if (u < 0 || u > 6) continue;
            for (int b = 0; b < 3; ++b) {
                int v = dx - b; if (v < 0 || v > 6) continue;
                s += sK[((a * 3 + b) * 3 + ci) * 49 + c * 1323 + u * 7 + v];
            }
        }
        W9[idx] = s;  // layout c*243 + ci*81 + dy*9 + dx
    }
    if (t < 2) {
        float s = bc2[t];
        for (int j = 0; j < 9; ++j) s += sBeta[t * 9 + j];
        Bt[t] = s;
    }
}

// Interior-only composite 9x9 conv. 32x32 tile/block, LDS 40x40x3, row stride 40
// (40%32=8 -> b128 collisions are 2-way = free). Border pixels get (wrong)
// zero-padded-9x9 values here; k_border overwrites them exactly afterwards.
__global__ __launch_bounds__(256) void k_conv(const float* __restrict__ x,
                                              const float* __restrict__ ws,
                                              float* __restrict__ ini) {
    __shared__ float sx[3][40][40];
    int b   = blockIdx.z;
    int gh0 = blockIdx.y * 32, gw0 = blockIdx.x * 32;
    int t = threadIdx.x;
    for (int idx = t; idx < 3 * 40 * 40; idx += 256) {
        int ci = idx / 1600;
        int rem = idx - ci * 1600;
        int rr = rem / 40, cc = rem - rr * 40;
        int gh = gh0 - 4 + rr, gw = gw0 - 4 + cc;
        float v = 0.f;
        if ((unsigned)gh < 320u && (unsigned)gw < 320u)
            v = x[(b * 3 + ci) * 102400 + gh * 320 + gw];
        sx[ci][rr][cc] = v;
    }
    __syncthreads();
    const float* W9g = ws + WS_W9;   // wave-uniform addresses -> s_load
    const float* Btg = ws + WS_BT;
    int r = t >> 3, cg = t & 7;
    int h = gh0 + r, w0c = gw0 + cg * 4;
    float acc0[4], acc1[4];
    float bt0 = Btg[0], bt1 = Btg[1];
    #pragma unroll
    for (int j = 0; j < 4; ++j) { acc0[j] = bt0; acc1[j] = bt1; }
    #pragma unroll
    for (int ci = 0; ci < 3; ++ci) {
        #pragma unroll
        for (int dy = 0; dy < 9; ++dy) {
            const float* xr = &sx[ci][r + dy][cg * 4];
            float4 xa = *(const float4*)(xr);
            float4 xb = *(const float4*)(xr + 4);
            float4 xc = *(const float4*)(xr + 8);
            float xv[12] = {xa.x, xa.y, xa.z, xa.w,
                            xb.x, xb.y, xb.z, xb.w,
                            xc.x, xc.y, xc.z, xc.w};
            #pragma unroll
            for (int dx = 0; dx < 9; ++dx) {
                float w0t = W9g[ci * 81 + dy * 9 + dx];
                float w1t = W9g[243 + ci * 81 + dy * 9 + dx];
                #pragma unroll
                for (int j = 0; j < 4; ++j) {
                    acc0[j] += w0t * xv[dx + j];
                    acc1[j] += w1t * xv[dx + j];
                }
            }
        }
    }
    size_t obase = (size_t)(b * 2) * 102400 + h * 320 + w0c;
    *(float4*)&ini[obase] = make_float4(acc0[0], acc0[1], acc0[2], acc0[3]);
    *(float4*)&ini[obase + 102400] = make_float4(acc1[0], acc1[1], acc1[2], acc1[3]);
}

// Exact border: one thread per (border pixel, out-channel). 20416 threads.
// K-decomposition with only-valid intermediate taps; v-loop unrolled for load ILP.
__global__ __launch_bounds__(256) void k_border(const float* __restrict__ x,
                                                const float* __restrict__ bc2,
                                                const float* __restrict__ ws,
                                                float* __restrict__ ini) {
    int tid = blockIdx.x * 256 + threadIdx.x;
    if (tid >= 20416) return;
    int c = tid & 1, pi = tid >> 1;
    int b = pi / 1276, j = pi % 1276;
    int h, w;
    if (j < 320)      { h = 0;           w = j; }
    else if (j < 640) { h = 319;         w = j - 320; }
    else if (j < 958) { h = 1 + j - 640; w = 0; }
    else              { h = 1 + j - 958; w = 319; }
    const float* K    = ws + WS_K;
    const float* Beta = ws + WS_BETA;
    float acc = bc2[c];
    for (int a = 0; a < 3; ++a) {
        int hh0 = h + a - 1;
        if ((unsigned)hh0 >= 320u) continue;
        for (int bb = 0; bb < 3; ++bb) {
            int ww0 = w + bb - 1;
            if ((unsigned)ww0 >= 320u) continue;
            acc += Beta[c * 9 + a * 3 + bb];
            for (int ci = 0; ci < 3; ++ci) {
                const float* Kc = K + ((a * 3 + bb) * 3 + ci) * 49 + c * 1323;
                const float* xb = x + (b * 3 + ci) * 102400;
                for (int u = 0; u < 7; ++u) {
                    int hx = hh0 + u - 3;
                    if ((unsigned)hx >= 320u) continue;
                    const float* xr = xb + hx * 320;
                    #pragma unroll
                    for (int v = 0; v < 7; ++v) {
                        int wx = ww0 + v - 3;
                        if ((unsigned)wx < 320u)
                            acc += Kc[u * 7 + v] * xr[wx];
                    }
                }
            }
        }
    }
    ini[(b * 2 + c) * 102400 + h * 320 + w] = acc;
}

// trans: outT[bc][p][l] = relu( sum_r M[p][r] * patchval[bc][l][r] )
// Staging: the block's 64 patches == a contiguous 20-row x 320-col strip ->
// coalesced row-major loads, scattered into sP (stride 68 for bank spread).
#define SPS 68
template <int MODE>
__global__ __launch_bounds__(256) void k_trans(const float* __restrict__ src,
                                               const float* __restrict__ wfm,
                                               const float* __restrict__ bfm,
                                               const float* __restrict__ ws,
                                               float* __restrict__ outT) {
    __shared__ float sM[100 * 50];    // sM[r*50 + (p - pg*50)]
    __shared__ float sP[100 * SPS];   // sP[r*SPS + li]
    int bc = blockIdx.x;   // 0..15
    int lg = blockIdx.y;   // 0..15 -> 64 patches (2 patch-rows x 32)
    int pg = blockIdx.z;   // 0..1  -> 50 p's each
    int t = threadIdx.x;
    const float* Mt = ws + WS_M;
    for (int i = t; i < 5000; i += 256) {
        int r = i / 50, p = i % 50;
        sM[i] = Mt[r * 100 + pg * 50 + p];
    }
    int b = bc >> 1, c = bc & 1;
    int row0 = lg * 20;    // image-row base of this block's strip
    float wf0 = 0.f, wf1 = 0.f, wf2 = 0.f, bf = 0.f;
    if (MODE == 1) { wf0 = wfm[c * 3 + 0]; wf1 = wfm[c * 3 + 1]; wf2 = wfm[c * 3 + 2]; bf = bfm[c]; }
    for (int e = t; e < 6400; e += 256) {
        int irow = e / 320, col = e % 320;
        int off = (row0 + irow) * 320 + col;
        float val;
        if (MODE == 0) {
            val = src[bc * 102400 + off];
        } else {
            val = (bf + src[(b * 3 + 0) * 102400 + off] * wf0
                      + src[(b * 3 + 1) * 102400 + off] * wf1
                      + src[(b * 3 + 2) * 102400 + off] * wf2) * 0.25f;
        }
        int li = (irow / 10) * 32 + col / 10;
        int r  = (irow % 10) * 10 + col % 10;
        sP[r * SPS + li] = val;
    }
    __syncthreads();
    if (t < 200) {
        int py = t / 8;        // 0..24 -> p0 = py*2
        int lx = t % 8;        // lo = lx*8
        int p0 = py * 2, lo = lx * 8;
        float acc[2][8];
        #pragma unroll
        for (int i = 0; i < 2; ++i)
            #pragma unroll
            for (int j = 0; j < 8; ++j) acc[i][j] = 0.f;
        for (int r = 0; r < 100; ++r) {
            float2 a  = *(const float2*)&sM[r * 50 + p0];
            float4 b0 = *(const float4*)&sP[r * SPS + lo];
            float4 b1 = *(const float4*)&sP[r * SPS + lo + 4];
            float av[2] = {a.x, a.y};
            float bv[8] = {b0.x, b0.y, b0.z, b0.w, b1.x, b1.y, b1.z, b1.w};
            #pragma unroll
            for (int i = 0; i < 2; ++i)
                #pragma unroll
                for (int j = 0; j < 8; ++j)
                    acc[i][j] += av[i] * bv[j];
        }
        #pragma unroll
        for (int i = 0; i < 2; ++i) {
            int pglob = pg * 50 + p0 + i;
            float* o = outT + (bc * 100 + pglob) * 1024 + lg * 64 + lo;
            float4 v0 = make_float4(fmaxf(acc[i][0], 0.f), fmaxf(acc[i][1], 0.f),
                                    fmaxf(acc[i][2], 0.f), fmaxf(acc[i][3], 0.f));
            float4 v1 = make_float4(fmaxf(acc[i][4], 0.f), fmaxf(acc[i][5], 0.f),
                                    fmaxf(acc[i][6], 0.f), fmaxf(acc[i][7], 0.f));
            *(float4*)&o[0] = v0;
            *(float4*)&o[4] = v1;
        }
    }
}

// att[bc][l][m] = sum_p uiT[bc][p][l] * ufT[bc][p][m] * 0.01
// 128x128 tile, 256 threads, 8x8 per thread, k-chunked LDS (20x128 x2).
#define AKC 20
__global__ __launch_bounds__(256) void k_att(const float* __restrict__ uiT,
                                             const float* __restrict__ ufT,
                                             float* __restrict__ out) {
    __shared__ float su[AKC][128];
    __shared__ float sv[AKC][128];
    int bc   = blockIdx.z;
    int row0 = blockIdx.y * 128;
    int col0 = blockIdx.x * 128;
    int t = threadIdx.x;
    int tx = t & 15, ty = t >> 4;
    const float* ub = uiT + bc * 102400;
    const float* vb = ufT + bc * 102400;
    float acc[8][8];
    #pragma unroll
    for (int i = 0; i < 8; ++i)
        #pragma unroll
        for (int j = 0; j < 8; ++j) acc[i][j] = 0.f;
    for (int k0 = 0; k0 < 100; k0 += AKC) {
        for (int e = t; e < AKC * 128; e += 256) {
            int kk = e >> 7, cc = e & 127;
            su[kk][cc] = ub[(k0 + kk) * 1024 + row0 + cc];
            sv[kk][cc] = vb[(k0 + kk) * 1024 + col0 + cc];
        }
        __syncthreads();
        #pragma unroll
        for (int kk = 0; kk < AKC; ++kk) {
            float4 a0 = *(const float4*)&su[kk][ty * 8];
            float4 a1 = *(const float4*)&su[kk][ty * 8 + 4];
            float4 b0 = *(const float4*)&sv[kk][tx * 8];
            float4 b1 = *(const float4*)&sv[kk][tx * 8 + 4];
            float av[8] = {a0.x, a0.y, a0.z, a0.w, a1.x, a1.y, a1.z, a1.w};
            float bv[8] = {b0.x, b0.y, b0.z, b0.w, b1.x, b1.y, b1.z, b1.w};
            #pragma unroll
            for (int i = 0; i < 8; ++i)
                #pragma unroll
                for (int j = 0; j < 8; ++j)
                    acc[i][j] += av[i] * bv[j];
        }
        __syncthreads();
    }
    #pragma unroll
    for (int i = 0; i < 8; ++i) {
        float* o = out + ((size_t)(bc * 1024 + row0 + ty * 8 + i)) * 1024 + col0 + tx * 8;
        float4 v0 = make_float4(acc[i][0] * 0.01f, acc[i][1] * 0.01f,
                                acc[i][2] * 0.01f, acc[i][3] * 0.01f);
        float4 v1 = make_float4(acc[i][4] * 0.01f, acc[i][5] * 0.01f,
                                acc[i][6] * 0.01f, acc[i][7] * 0.01f);
        *(float4*)&o[0] = v0;
        *(float4*)&o[4] = v1;
    }
}

extern "C" void kernel_launch(void* const* d_in, const int* in_sizes, int n_in,
                              void* d_out, int out_size, void* d_ws, size_t ws_size,
                              hipStream_t stream) {
    const float* x       = (const float*)d_in[0];
    const float* w_conv1 = (const float*)d_in[1];
    const float* b_conv1 = (const float*)d_in[2];
    const float* w_conv2 = (const float*)d_in[3];
    const float* b_conv2 = (const float*)d_in[4];
    const float* w_fm    = (const float*)d_in[5];
    const float* b_fm    = (const float*)d_in[6];
    const float* w_lin1  = (const float*)d_in[7];
    const float* w_lin2  = (const float*)d_in[8];
    float* out = (float*)d_out;
    float* ws  = (float*)d_ws;

    k_prepM<<<40, 256, 0, stream>>>(w_lin1, w_lin2, ws + WS_M);
    k_prepW<<<1, 256, 0, stream>>>(w_conv1, b_conv1, w_conv2, b_conv2, ws);
    k_conv<<<dim3(10, 10, 8), 256, 0, stream>>>(x, ws, ws + WS_INI);
    k_border<<<80, 256, 0, stream>>>(x, b_conv2, ws, ws + WS_INI);
    dim3 gt(16, 16, 2);
    k_trans<0><<<gt, 256, 0, stream>>>(ws + WS_INI, w_fm, b_fm, ws, ws + WS_UIT);
    k_trans<1><<<gt, 256, 0, stream>>>(x, w_fm, b_fm, ws, ws + WS_UFT);
    dim3 ga(8, 8, 16);
    k_att<<<ga, 256, 0, stream>>>(ws + WS_UIT, ws + WS_UFT, out);
}

// Round 4
// 250.706 us; speedup vs baseline: 1.8122x; 1.3973x over previous
//
#include <hip/hip_runtime.h>

// Workspace layout (float offsets)
#define WS_M      0        // Mt[r*100+p] = (w_lin2 @ w_lin1)^T, 10000 floats
#define WS_K      10000    // K[c][a][b][ci][u][v], 2646 floats
#define WS_BETA   12646    // beta[c][a][b], 18 floats
#define WS_W9     12664    // W9[c][ci][dy][dx], 486 floats
#define WS_BT     13150    // beta_tot[c] (interior combined bias), 2 floats
#define WS_INI    16384    // ini[b][c][h][w], 1,638,400 floats
#define WS_UIT    (16384 + 1638400)      // uiT[bc][p][l], 1,638,400 floats
#define WS_UFT    (16384 + 2*1638400)    // ufT[bc][p][l], 1,638,400 floats

// M[p][r] = sum_q w_lin2[p,q] * w_lin1[q,r]; stored TRANSPOSED: Mt[r*100+p]
__global__ __launch_bounds__(256) void k_prepM(const float* __restrict__ wl1,
                                               const float* __restrict__ wl2,
                                               float* __restrict__ Mt) {
    int idx = blockIdx.x * 256 + threadIdx.x;
    if (idx >= 10000) return;
    int p = idx / 100, r = idx % 100;
    float s = 0.f;
    for (int q = 0; q < 200; ++q)
        s += wl2[p * 200 + q] * wl1[q * 100 + r];
    Mt[r * 100 + p] = s;
}

// Composite conv weights: K, beta, W9, beta_tot. Single block; weights staged in LDS.
__global__ __launch_bounds__(256) void k_prepW(const float* __restrict__ wc1,
                                               const float* __restrict__ bc1,
                                               const float* __restrict__ wc2,
                                               const float* __restrict__ bc2,
                                               float* __restrict__ ws) {
    float* K    = ws + WS_K;
    float* Beta = ws + WS_BETA;
    float* W9   = ws + WS_W9;
    float* Bt   = ws + WS_BT;
    __shared__ float swc1[9408];   // 64*3*49
    __shared__ float swc2[1152];   // 2*64*9
    __shared__ float sK[2646];
    __shared__ float sBeta[18];
    int t = threadIdx.x;
    for (int i = t; i < 9408; i += 256) swc1[i] = wc1[i];
    for (int i = t; i < 1152; i += 256) swc2[i] = wc2[i];
    __syncthreads();
    for (int idx = t; idx < 2646; idx += 256) {
        int v = idx % 7; int t1 = idx / 7;
        int u = t1 % 7;  int t2 = t1 / 7;
        int ci = t2 % 3; int t3 = t2 / 3;
        int b = t3 % 3;  int t4 = t3 / 3;
        int a = t4 % 3;  int c = t4 / 3;
        float s = 0.f;
        for (int c64 = 0; c64 < 64; ++c64)
            s += swc2[((c * 64 + c64) * 3 + a) * 3 + b] *
                 swc1[((c64 * 3 + ci) * 7 + u) * 7 + v];
        sK[idx] = s; K[idx] = s;
    }
    if (t < 18) {
        int b = t % 3; int a = (t / 3) % 3; int c = t / 9;
        float s = 0.f;
        for (int c64 = 0; c64 < 64; ++c64)
            s += swc2[((c * 64 + c64) * 3 + a) * 3 + b] * bc1[c64];
        sBeta[t] = s; Beta[t] = s;
    }
    __syncthreads();
    for (int idx = t; idx < 486; idx += 256) {
        int dx = idx % 9; int t1 = idx / 9;
        int dy = t1 % 9;  int t2 = t1 / 9;
        int ci = t2 % 3;  int c = t2 / 3;
        float s = 0.f;
        for (int a = 0; a < 3; ++a) {
            int u = dy - a; if (u < 0 || u > 6) continue;
            for (int b = 0; b < 3; ++b) {
                int v = dx - b; if (v < 0 || v > 6) continue;
                s += sK[((a * 3 + b) * 3 + ci) * 49 + c * 1323 + u * 7 + v];
            }
        }
        W9[idx] = s;  // layout c*243 + ci*81 + dy*9 + dx
    }
    if (t < 2) {
        float s = bc2[t];
        for (int j = 0; j < 9; ++j) s += sBeta[t * 9 + j];
        Bt[t] = s;
    }
}

// Interior-only composite 9x9 conv. 32x32 tile/block, LDS 40x40x3, row stride 40
// (40%32=8 -> b128 collisions are 2-way = free). Border pixels get (wrong)
// zero-padded-9x9 values here; k_border overwrites them exactly afterwards.
__global__ __launch_bounds__(256) void k_conv(const float* __restrict__ x,
                                              const float* __restrict__ ws,
                                              float* __restrict__ ini) {
    __shared__ float sx[3][40][40];
    int b   = blockIdx.z;
    int gh0 = blockIdx.y * 32, gw0 = blockIdx.x * 32;
    int t = threadIdx.x;
    for (int idx = t; idx < 3 * 40 * 40; idx += 256) {
        int ci = idx / 1600;
        int rem = idx - ci * 1600;
        int rr = rem / 40, cc = rem - rr * 40;
        int gh = gh0 - 4 + rr, gw = gw0 - 4 + cc;
        float v = 0.f;
        if ((unsigned)gh < 320u && (unsigned)gw < 320u)
            v = x[(b * 3 + ci) * 102400 + gh * 320 + gw];
        sx[ci][rr][cc] = v;
    }
    __syncthreads();
    const float* W9g = ws + WS_W9;   // wave-uniform addresses -> s_load
    const float* Btg = ws + WS_BT;
    int r = t >> 3, cg = t & 7;
    int h = gh0 + r, w0c = gw0 + cg * 4;
    float acc0[4], acc1[4];
    float bt0 = Btg[0], bt1 = Btg[1];
    #pragma unroll
    for (int j = 0; j < 4; ++j) { acc0[j] = bt0; acc1[j] = bt1; }
    #pragma unroll
    for (int ci = 0; ci < 3; ++ci) {
        #pragma unroll
        for (int dy = 0; dy < 9; ++dy) {
            const float* xr = &sx[ci][r + dy][cg * 4];
            float4 xa = *(const float4*)(xr);
            float4 xb = *(const float4*)(xr + 4);
            float4 xc = *(const float4*)(xr + 8);
            float xv[12] = {xa.x, xa.y, xa.z, xa.w,
                            xb.x, xb.y, xb.z, xb.w,
                            xc.x, xc.y, xc.z, xc.w};
            #pragma unroll
            for (int dx = 0; dx < 9; ++dx) {
                float w0t = W9g[ci * 81 + dy * 9 + dx];
                float w1t = W9g[243 + ci * 81 + dy * 9 + dx];
                #pragma unroll
                for (int j = 0; j < 4; ++j) {
                    acc0[j] += w0t * xv[dx + j];
                    acc1[j] += w1t * xv[dx + j];
                }
            }
        }
    }
    size_t obase = (size_t)(b * 2) * 102400 + h * 320 + w0c;
    *(float4*)&ini[obase] = make_float4(acc0[0], acc0[1], acc0[2], acc0[3]);
    *(float4*)&ini[obase + 102400] = make_float4(acc1[0], acc1[1], acc1[2], acc1[3]);
}

// Exact border, wave-parallel: one WAVE per (border pixel, out-channel).
// Lanes enumerate the (a,bb,ci,u) reduction space (189 row-jobs, <=3/lane),
// each doing <=7 predicated K/x loads; 6-step shuffle reduce; lane 0 writes.
__global__ __launch_bounds__(256) void k_border(const float* __restrict__ x,
                                                const float* __restrict__ bc2,
                                                const float* __restrict__ ws,
                                                float* __restrict__ ini) {
    int wid  = (blockIdx.x * 256 + threadIdx.x) >> 6;   // 0..20415 (grid exact)
    int lane = threadIdx.x & 63;
    int c = wid & 1, pi = wid >> 1;
    int b = pi / 1276, j = pi % 1276;
    int h, w;
    if (j < 320)      { h = 0;           w = j; }
    else if (j < 640) { h = 319;         w = j - 320; }
    else if (j < 958) { h = 1 + j - 640; w = 0; }
    else              { h = 1 + j - 958; w = 319; }
    const float* K    = ws + WS_K;
    const float* Beta = ws + WS_BETA;
    float acc = 0.f;
    #pragma unroll
    for (int rep = 0; rep < 3; ++rep) {
        int e = lane + rep * 64;
        if (e < 189) {
            int a = e / 63;   int rem  = e - a * 63;
            int bb = rem / 21; int rem2 = rem - bb * 21;
            int ci = rem2 / 7; int u = rem2 - ci * 7;
            int hh0 = h + a - 1;
            int ww0 = w + bb - 1;
            bool abv = ((unsigned)hh0 < 320u) & ((unsigned)ww0 < 320u);
            if (abv && ci == 0 && u == 0) acc += Beta[c * 9 + a * 3 + bb];
            int hx = hh0 + u - 3;
            if (abv && (unsigned)hx < 320u) {
                const float* Kc = K + ((a * 3 + bb) * 3 + ci) * 49 + c * 1323 + u * 7;
                const float* xr = x + (b * 3 + ci) * 102400 + hx * 320;
                #pragma unroll
                for (int v = 0; v < 7; ++v) {
                    int wx = ww0 + v - 3;
                    if ((unsigned)wx < 320u)
                        acc += Kc[v] * xr[wx];
                }
            }
        }
    }
    #pragma unroll
    for (int off = 32; off > 0; off >>= 1)
        acc += __shfl_down(acc, off, 64);
    if (lane == 0)
        ini[(b * 2 + c) * 102400 + h * 320 + w] = acc + bc2[c];
}

// trans: outT[bc][p][l] = relu( sum_r M[p][r] * patchval[bc][l][r] )
// Staging: the block's 64 patches == a contiguous 20-row x 320-col strip ->
// coalesced row-major loads, scattered into sP (stride 68 for bank spread).
#define SPS 68
template <int MODE>
__global__ __launch_bounds__(256) void k_trans(const float* __restrict__ src,
                                               const float* __restrict__ wfm,
                                               const float* __restrict__ bfm,
                                               const float* __restrict__ ws,
                                               float* __restrict__ outT) {
    __shared__ float sM[100 * 50];    // sM[r*50 + (p - pg*50)]
    __shared__ float sP[100 * SPS];   // sP[r*SPS + li]
    int bc = blockIdx.x;   // 0..15
    int lg = blockIdx.y;   // 0..15 -> 64 patches (2 patch-rows x 32)
    int pg = blockIdx.z;   // 0..1  -> 50 p's each
    int t = threadIdx.x;
    const float* Mt = ws + WS_M;
    for (int i = t; i < 5000; i += 256) {
        int r = i / 50, p = i % 50;
        sM[i] = Mt[r * 100 + pg * 50 + p];
    }
    int b = bc >> 1, c = bc & 1;
    int row0 = lg * 20;    // image-row base of this block's strip
    float wf0 = 0.f, wf1 = 0.f, wf2 = 0.f, bf = 0.f;
    if (MODE == 1) { wf0 = wfm[c * 3 + 0]; wf1 = wfm[c * 3 + 1]; wf2 = wfm[c * 3 + 2]; bf = bfm[c]; }
    for (int e = t; e < 6400; e += 256) {
        int irow = e / 320, col = e % 320;
        int off = (row0 + irow) * 320 + col;
        float val;
        if (MODE == 0) {
            val = src[bc * 102400 + off];
        } else {
            val = (bf + src[(b * 3 + 0) * 102400 + off] * wf0
                      + src[(b * 3 + 1) * 102400 + off] * wf1
                      + src[(b * 3 + 2) * 102400 + off] * wf2) * 0.25f;
        }
        int li = (irow / 10) * 32 + col / 10;
        int r  = (irow % 10) * 10 + col % 10;
        sP[r * SPS + li] = val;
    }
    __syncthreads();
    if (t < 200) {
        int py = t / 8;        // 0..24 -> p0 = py*2
        int lx = t % 8;        // lo = lx*8
        int p0 = py * 2, lo = lx * 8;
        float acc[2][8];
        #pragma unroll
        for (int i = 0; i < 2; ++i)
            #pragma unroll
            for (int j = 0; j < 8; ++j) acc[i][j] = 0.f;
        for (int r = 0; r < 100; ++r) {
            float2 a  = *(const float2*)&sM[r * 50 + p0];
            float4 b0 = *(const float4*)&sP[r * SPS + lo];
            float4 b1 = *(const float4*)&sP[r * SPS + lo + 4];
            float av[2] = {a.x, a.y};
            float bv[8] = {b0.x, b0.y, b0.z, b0.w, b1.x, b1.y, b1.z, b1.w};
            #pragma unroll
            for (int i = 0; i < 2; ++i)
                #pragma unroll
                for (int j = 0; j < 8; ++j)
                    acc[i][j] += av[i] * bv[j];
        }
        #pragma unroll
        for (int i = 0; i < 2; ++i) {
            int pglob = pg * 50 + p0 + i;
            float* o = outT + (bc * 100 + pglob) * 1024 + lg * 64 + lo;
            float4 v0 = make_float4(fmaxf(acc[i][0], 0.f), fmaxf(acc[i][1], 0.f),
                                    fmaxf(acc[i][2], 0.f), fmaxf(acc[i][3], 0.f));
            float4 v1 = make_float4(fmaxf(acc[i][4], 0.f), fmaxf(acc[i][5], 0.f),
                                    fmaxf(acc[i][6], 0.f), fmaxf(acc[i][7], 0.f));
            *(float4*)&o[0] = v0;
            *(float4*)&o[4] = v1;
        }
    }
}

// att[bc][l][m] = sum_p uiT[bc][p][l] * ufT[bc][p][m] * 0.01
// 128x128 tile, 256 threads, 8x8 per thread, k-chunked LDS (20x128 x2).
#define AKC 20
__global__ __launch_bounds__(256) void k_att(const float* __restrict__ uiT,
                                             const float* __restrict__ ufT,
                                             float* __restrict__ out) {
    __shared__ float su[AKC][128];
    __shared__ float sv[AKC][128];
    int bc   = blockIdx.z;
    int row0 = blockIdx.y * 128;
    int col0 = blockIdx.x * 128;
    int t = threadIdx.x;
    int tx = t & 15, ty = t >> 4;
    const float* ub = uiT + bc * 102400;
    const float* vb = ufT + bc * 102400;
    float acc[8][8];
    #pragma unroll
    for (int i = 0; i < 8; ++i)
        #pragma unroll
        for (int j = 0; j < 8; ++j) acc[i][j] = 0.f;
    for (int k0 = 0; k0 < 100; k0 += AKC) {
        for (int e = t; e < AKC * 128; e += 256) {
            int kk = e >> 7, cc = e & 127;
            su[kk][cc] = ub[(k0 + kk) * 1024 + row0 + cc];
            sv[kk][cc] = vb[(k0 + kk) * 1024 + col0 + cc];
        }
        __syncthreads();
        #pragma unroll
        for (int kk = 0; kk < AKC; ++kk) {
            float4 a0 = *(const float4*)&su[kk][ty * 8];
            float4 a1 = *(const float4*)&su[kk][ty * 8 + 4];
            float4 b0 = *(const float4*)&sv[kk][tx * 8];
            float4 b1 = *(const float4*)&sv[kk][tx * 8 + 4];
            float av[8] = {a0.x, a0.y, a0.z, a0.w, a1.x, a1.y, a1.z, a1.w};
            float bv[8] = {b0.x, b0.y, b0.z, b0.w, b1.x, b1.y, b1.z, b1.w};
            #pragma unroll
            for (int i = 0; i < 8; ++i)
                #pragma unroll
                for (int j = 0; j < 8; ++j)
                    acc[i][j] += av[i] * bv[j];
        }
        __syncthreads();
    }
    #pragma unroll
    for (int i = 0; i < 8; ++i) {
        float* o = out + ((size_t)(bc * 1024 + row0 + ty * 8 + i)) * 1024 + col0 + tx * 8;
        float4 v0 = make_float4(acc[i][0] * 0.01f, acc[i][1] * 0.01f,
                                acc[i][2] * 0.01f, acc[i][3] * 0.01f);
        float4 v1 = make_float4(acc[i][4] * 0.01f, acc[i][5] * 0.01f,
                                acc[i][6] * 0.01f, acc[i][7] * 0.01f);
        *(float4*)&o[0] = v0;
        *(float4*)&o[4] = v1;
    }
}

extern "C" void kernel_launch(void* const* d_in, const int* in_sizes, int n_in,
                              void* d_out, int out_size, void* d_ws, size_t ws_size,
                              hipStream_t stream) {
    const float* x       = (const float*)d_in[0];
    const float* w_conv1 = (const float*)d_in[1];
    const float* b_conv1 = (const float*)d_in[2];
    const float* w_conv2 = (const float*)d_in[3];
    const float* b_conv2 = (const float*)d_in[4];
    const float* w_fm    = (const float*)d_in[5];
    const float* b_fm    = (const float*)d_in[6];
    const float* w_lin1  = (const float*)d_in[7];
    const float* w_lin2  = (const float*)d_in[8];
    float* out = (float*)d_out;
    float* ws  = (float*)d_ws;

    k_prepM<<<40, 256, 0, stream>>>(w_lin1, w_lin2, ws + WS_M);
    k_prepW<<<1, 256, 0, stream>>>(w_conv1, b_conv1, w_conv2, b_conv2, ws);
    k_conv<<<dim3(10, 10, 8), 256, 0, stream>>>(x, ws, ws + WS_INI);
    k_border<<<5104, 256, 0, stream>>>(x, b_conv2, ws, ws + WS_INI);  // 20416 waves
    dim3 gt(16, 16, 2);
    k_trans<0><<<gt, 256, 0, stream>>>(ws + WS_INI, w_fm, b_fm, ws, ws + WS_UIT);
    k_trans<1><<<gt, 256, 0, stream>>>(x, w_fm, b_fm, ws, ws + WS_UFT);
    dim3 ga(8, 8, 16);
    k_att<<<ga, 256, 0, stream>>>(ws + WS_UIT, ws + WS_UFT, out);
}

// Round 5
// 222.983 us; speedup vs baseline: 2.0375x; 1.1243x over previous
//
#include <hip/hip_runtime.h>

// Workspace layout (float offsets)
#define WS_M      0        // Mt[r*100+p] = (w_lin2 @ w_lin1)^T, 10000 floats
#define WS_K      10000    // K[c][a][b][ci][u][v], 2646 floats
#define WS_BETA   12646    // beta[c][a][b], 18 floats
#define WS_W9     12664    // W9[c][ci][dy][dx], 486 floats
#define WS_BT     13150    // beta_tot[c] (interior combined bias), 2 floats
#define WS_INI    16384    // ini[b][c][h][w], 1,638,400 floats
#define WS_UIT    (16384 + 1638400)      // uiL[bc][l][p128] bf16, 2,097,152 ushorts (fits)
#define WS_UFT    (16384 + 2*1638400)    // ufL[bc][l][p128] bf16

typedef short bf16x8 __attribute__((ext_vector_type(8)));
typedef float f32x4  __attribute__((ext_vector_type(4)));

__device__ inline ushort f2bf(float f) {   // round-to-nearest-even
    unsigned u = __float_as_uint(f);
    unsigned r = (u + 0x7fffu + ((u >> 16) & 1u)) >> 16;
    return (ushort)r;
}

// M[p][r] = sum_q w_lin2[p,q] * w_lin1[q,r]; stored TRANSPOSED: Mt[r*100+p]
__global__ __launch_bounds__(256) void k_prepM(const float* __restrict__ wl1,
                                               const float* __restrict__ wl2,
                                               float* __restrict__ Mt) {
    int idx = blockIdx.x * 256 + threadIdx.x;
    if (idx >= 10000) return;
    int p = idx / 100, r = idx % 100;
    float s = 0.f;
    for (int q = 0; q < 200; ++q)
        s += wl2[p * 200 + q] * wl1[q * 100 + r];
    Mt[r * 100 + p] = s;
}

// Composite conv weights: K, beta, W9, beta_tot. Single block; weights staged in LDS.
__global__ __launch_bounds__(256) void k_prepW(const float* __restrict__ wc1,
                                               const float* __restrict__ bc1,
                                               const float* __restrict__ wc2,
                                               const float* __restrict__ bc2,
                                               float* __restrict__ ws) {
    float* K    = ws + WS_K;
    float* Beta = ws + WS_BETA;
    float* W9   = ws + WS_W9;
    float* Bt   = ws + WS_BT;
    __shared__ float swc1[9408];   // 64*3*49
    __shared__ float swc2[1152];   // 2*64*9
    __shared__ float sK[2646];
    __shared__ float sBeta[18];
    int t = threadIdx.x;
    for (int i = t; i < 9408; i += 256) swc1[i] = wc1[i];
    for (int i = t; i < 1152; i += 256) swc2[i] = wc2[i];
    __syncthreads();
    for (int idx = t; idx < 2646; idx += 256) {
        int v = idx % 7; int t1 = idx / 7;
        int u = t1 % 7;  int t2 = t1 / 7;
        int ci = t2 % 3; int t3 = t2 / 3;
        int b = t3 % 3;  int t4 = t3 / 3;
        int a = t4 % 3;  int c = t4 / 3;
        float s = 0.f;
        for (int c64 = 0; c64 < 64; ++c64)
            s += swc2[((c * 64 + c64) * 3 + a) * 3 + b] *
                 swc1[((c64 * 3 + ci) * 7 + u) * 7 + v];
        sK[idx] = s; K[idx] = s;
    }
    if (t < 18) {
        int b = t % 3; int a = (t / 3) % 3; int c = t / 9;
        float s = 0.f;
        for (int c64 = 0; c64 < 64; ++c64)
            s += swc2[((c * 64 + c64) * 3 + a) * 3 + b] * bc1[c64];
        sBeta[t] = s; Beta[t] = s;
    }
    __syncthreads();
    for (int idx = t; idx < 486; idx += 256) {
        int dx = idx % 9; int t1 = idx / 9;
        int dy = t1 % 9;  int t2 = t1 / 9;
        int ci = t2 % 3;  int c = t2 / 3;
        float s = 0.f;
        for (int a = 0; a < 3; ++a) {
            int u = dy - a; if (u < 0 || u > 6) continue;
            for (int b = 0; b < 3; ++b) {
                int v = dx - b; if (v < 0 || v > 6) continue;
                s += sK[((a * 3 + b) * 3 + ci) * 49 + c * 1323 + u * 7 + v];
            }
        }
        W9[idx] = s;  // layout c*243 + ci*81 + dy*9 + dx
    }
    if (t < 2) {
        float s = bc2[t];
        for (int j = 0; j < 9; ++j) s += sBeta[t * 9 + j];
        Bt[t] = s;
    }
}

// Interior-only composite 9x9 conv. 32x32 tile/block, LDS 40x40x3, row stride 40
// (40%32=8 -> b128 collisions are 2-way = free). Border pixels get (wrong)
// zero-padded-9x9 values here; k_border overwrites them exactly afterwards.
__global__ __launch_bounds__(256) void k_conv(const float* __restrict__ x,
                                              const float* __restrict__ ws,
                                              float* __restrict__ ini) {
    __shared__ float sx[3][40][40];
    int b   = blockIdx.z;
    int gh0 = blockIdx.y * 32, gw0 = blockIdx.x * 32;
    int t = threadIdx.x;
    for (int idx = t; idx < 3 * 40 * 40; idx += 256) {
        int ci = idx / 1600;
        int rem = idx - ci * 1600;
        int rr = rem / 40, cc = rem - rr * 40;
        int gh = gh0 - 4 + rr, gw = gw0 - 4 + cc;
        float v = 0.f;
        if ((unsigned)gh < 320u && (unsigned)gw < 320u)
            v = x[(b * 3 + ci) * 102400 + gh * 320 + gw];
        sx[ci][rr][cc] = v;
    }
    __syncthreads();
    const float* W9g = ws + WS_W9;   // wave-uniform addresses -> s_load
    const float* Btg = ws + WS_BT;
    int r = t >> 3, cg = t & 7;
    int h = gh0 + r, w0c = gw0 + cg * 4;
    float acc0[4], acc1[4];
    float bt0 = Btg[0], bt1 = Btg[1];
    #pragma unroll
    for (int j = 0; j < 4; ++j) { acc0[j] = bt0; acc1[j] = bt1; }
    #pragma unroll
    for (int ci = 0; ci < 3; ++ci) {
        #pragma unroll
        for (int dy = 0; dy < 9; ++dy) {
            const float* xr = &sx[ci][r + dy][cg * 4];
            float4 xa = *(const float4*)(xr);
            float4 xb = *(const float4*)(xr + 4);
            float4 xc = *(const float4*)(xr + 8);
            float xv[12] = {xa.x, xa.y, xa.z, xa.w,
                            xb.x, xb.y, xb.z, xb.w,
                            xc.x, xc.y, xc.z, xc.w};
            #pragma unroll
            for (int dx = 0; dx < 9; ++dx) {
                float w0t = W9g[ci * 81 + dy * 9 + dx];
                float w1t = W9g[243 + ci * 81 + dy * 9 + dx];
                #pragma unroll
                for (int j = 0; j < 4; ++j) {
                    acc0[j] += w0t * xv[dx + j];
                    acc1[j] += w1t * xv[dx + j];
                }
            }
        }
    }
    size_t obase = (size_t)(b * 2) * 102400 + h * 320 + w0c;
    *(float4*)&ini[obase] = make_float4(acc0[0], acc0[1], acc0[2], acc0[3]);
    *(float4*)&ini[obase + 102400] = make_float4(acc1[0], acc1[1], acc1[2], acc1[3]);
}

// Exact border, wave-parallel: one WAVE per (border pixel, out-channel).
__global__ __launch_bounds__(256) void k_border(const float* __restrict__ x,
                                                const float* __restrict__ bc2,
                                                const float* __restrict__ ws,
                                                float* __restrict__ ini) {
    int wid  = (blockIdx.x * 256 + threadIdx.x) >> 6;   // 0..20415 (grid exact)
    int lane = threadIdx.x & 63;
    int c = wid & 1, pi = wid >> 1;
    int b = pi / 1276, j = pi % 1276;
    int h, w;
    if (j < 320)      { h = 0;           w = j; }
    else if (j < 640) { h = 319;         w = j - 320; }
    else if (j < 958) { h = 1 + j - 640; w = 0; }
    else              { h = 1 + j - 958; w = 319; }
    const float* K    = ws + WS_K;
    const float* Beta = ws + WS_BETA;
    float acc = 0.f;
    #pragma unroll
    for (int rep = 0; rep < 3; ++rep) {
        int e = lane + rep * 64;
        if (e < 189) {
            int a = e / 63;   int rem  = e - a * 63;
            int bb = rem / 21; int rem2 = rem - bb * 21;
            int ci = rem2 / 7; int u = rem2 - ci * 7;
            int hh0 = h + a - 1;
            int ww0 = w + bb - 1;
            bool abv = ((unsigned)hh0 < 320u) & ((unsigned)ww0 < 320u);
            if (abv && ci == 0 && u == 0) acc += Beta[c * 9 + a * 3 + bb];
            int hx = hh0 + u - 3;
            if (abv && (unsigned)hx < 320u) {
                const float* Kc = K + ((a * 3 + bb) * 3 + ci) * 49 + c * 1323 + u * 7;
                const float* xr = x + (b * 3 + ci) * 102400 + hx * 320;
                #pragma unroll
                for (int v = 0; v < 7; ++v) {
                    int wx = ww0 + v - 3;
                    if ((unsigned)wx < 320u)
                        acc += Kc[v] * xr[wx];
                }
            }
        }
    }
    #pragma unroll
    for (int off = 32; off > 0; off >>= 1)
        acc += __shfl_down(acc, off, 64);
    if (lane == 0)
        ini[(b * 2 + c) * 102400 + h * 320 + w] = acc + bc2[c];
}

// trans: out bf16, l-major: uiL[bc][l][p128] = relu(sum_r M[p][r]*patch[l][r]).
// p 100..127 zero-padded (by pg==1 blocks) so k_att can run k=128 MFMA.
#define SPS 68
template <int MODE>
__global__ __launch_bounds__(256) void k_trans(const float* __restrict__ src,
                                               const float* __restrict__ wfm,
                                               const float* __restrict__ bfm,
                                               const float* __restrict__ ws,
                                               ushort* __restrict__ outL) {
    __shared__ float sM[100 * 50];    // sM[r*50 + (p - pg*50)]
    __shared__ float sP[100 * SPS];   // sP[r*SPS + li]
    int bc = blockIdx.x;   // 0..15
    int lg = blockIdx.y;   // 0..15 -> 64 patches (2 patch-rows x 32)
    int pg = blockIdx.z;   // 0..1  -> 50 p's each
    int t = threadIdx.x;
    const float* Mt = ws + WS_M;
    for (int i = t; i < 5000; i += 256) {
        int r = i / 50, p = i % 50;
        sM[i] = Mt[r * 100 + pg * 50 + p];
    }
    int b = bc >> 1, c = bc & 1;
    int row0 = lg * 20;    // image-row base of this block's strip
    float wf0 = 0.f, wf1 = 0.f, wf2 = 0.f, bf = 0.f;
    if (MODE == 1) { wf0 = wfm[c * 3 + 0]; wf1 = wfm[c * 3 + 1]; wf2 = wfm[c * 3 + 2]; bf = bfm[c]; }
    for (int e = t; e < 6400; e += 256) {
        int irow = e / 320, col = e % 320;
        int off = (row0 + irow) * 320 + col;
        float val;
        if (MODE == 0) {
            val = src[bc * 102400 + off];
        } else {
            val = (bf + src[(b * 3 + 0) * 102400 + off] * wf0
                      + src[(b * 3 + 1) * 102400 + off] * wf1
                      + src[(b * 3 + 2) * 102400 + off] * wf2) * 0.25f;
        }
        int li = (irow / 10) * 32 + col / 10;
        int r  = (irow % 10) * 10 + col % 10;
        sP[r * SPS + li] = val;
    }
    if (pg == 1) {   // zero the p-pad [100,128) for this block's 64 l's
        for (int e = t; e < 64 * 28; e += 256) {
            int l = lg * 64 + e / 28, pp = 100 + e % 28;
            outL[((size_t)bc * 1024 + l) * 128 + pp] = 0;
        }
    }
    __syncthreads();
    if (t < 200) {
        int py = t / 8;        // 0..24 -> p0 = py*2
        int lx = t % 8;        // lo = lx*8
        int p0 = py * 2, lo = lx * 8;
        float acc[2][8];
        #pragma unroll
        for (int i = 0; i < 2; ++i)
            #pragma unroll
            for (int j = 0; j < 8; ++j) acc[i][j] = 0.f;
        for (int r = 0; r < 100; ++r) {
            float2 a  = *(const float2*)&sM[r * 50 + p0];
            float4 b0 = *(const float4*)&sP[r * SPS + lo];
            float4 b1 = *(const float4*)&sP[r * SPS + lo + 4];
            float av[2] = {a.x, a.y};
            float bv[8] = {b0.x, b0.y, b0.z, b0.w, b1.x, b1.y, b1.z, b1.w};
            #pragma unroll
            for (int i = 0; i < 2; ++i)
                #pragma unroll
                for (int j = 0; j < 8; ++j)
                    acc[i][j] += av[i] * bv[j];
        }
        int pbase = pg * 50 + p0;   // even -> 4B-aligned ushort2 store
        #pragma unroll
        for (int j = 0; j < 8; ++j) {
            int l = lg * 64 + lo + j;
            unsigned v0 = f2bf(fmaxf(acc[0][j], 0.f));
            unsigned v1 = f2bf(fmaxf(acc[1][j], 0.f));
            *(unsigned*)&outL[((size_t)bc * 1024 + l) * 128 + pbase] = v0 | (v1 << 16);
        }
    }
}

// att[bc][l][m] = (1/100) * sum_p ui[l][p]*uf[m][p], bf16 MFMA 16x16x32.
// 128x128 tile/block, 4 waves 2x2, each wave 64x64 = 4x4 mfma tiles.
// Fragments straight from global (l-major bf16, k contiguous): 16B/lane loads.
__global__ __launch_bounds__(256) void k_att(const ushort* __restrict__ ui,
                                             const ushort* __restrict__ uf,
                                             float* __restrict__ out) {
    int bc   = blockIdx.z;
    int row0 = blockIdx.y * 128, col0 = blockIdx.x * 128;
    int wave = threadIdx.x >> 6, lane = threadIdx.x & 63;
    int r0 = row0 + (wave >> 1) * 64;
    int c0 = col0 + (wave & 1) * 64;
    int m = lane & 15, quad = lane >> 4;
    const ushort* ub = ui + (size_t)bc * 1024 * 128;
    const ushort* vb = uf + (size_t)bc * 1024 * 128;
    f32x4 acc[4][4];
    #pragma unroll
    for (int i = 0; i < 4; ++i)
        #pragma unroll
        for (int j = 0; j < 4; ++j)
            acc[i][j] = (f32x4){0.f, 0.f, 0.f, 0.f};
    #pragma unroll
    for (int k0 = 0; k0 < 128; k0 += 32) {
        bf16x8 af[4], bfr[4];
        #pragma unroll
        for (int i = 0; i < 4; ++i)
            af[i] = *(const bf16x8*)&ub[(size_t)(r0 + i * 16 + m) * 128 + k0 + quad * 8];
        #pragma unroll
        for (int j = 0; j < 4; ++j)
            bfr[j] = *(const bf16x8*)&vb[(size_t)(c0 + j * 16 + m) * 128 + k0 + quad * 8];
        #pragma unroll
        for (int i = 0; i < 4; ++i)
            #pragma unroll
            for (int j = 0; j < 4; ++j)
                acc[i][j] = __builtin_amdgcn_mfma_f32_16x16x32_bf16(af[i], bfr[j], acc[i][j], 0, 0, 0);
    }
    // C/D: col = lane&15, row = quad*4 + reg (m89/m91-verified)
    #pragma unroll
    for (int i = 0; i < 4; ++i) {
        #pragma unroll
        for (int r = 0; r < 4; ++r) {
            int row = r0 + i * 16 + quad * 4 + r;
            float* o = out + ((size_t)bc * 1024 + row) * 1024;
            #pragma unroll
            for (int j = 0; j < 4; ++j)
                o[c0 + j * 16 + m] = acc[i][j][r] * 0.01f;
        }
    }
}

extern "C" void kernel_launch(void* const* d_in, const int* in_sizes, int n_in,
                              void* d_out, int out_size, void* d_ws, size_t ws_size,
                              hipStream_t stream) {
    const float* x       = (const float*)d_in[0];
    const float* w_conv1 = (const float*)d_in[1];
    const float* b_conv1 = (const float*)d_in[2];
    const float* w_conv2 = (const float*)d_in[3];
    const float* b_conv2 = (const float*)d_in[4];
    const float* w_fm    = (const float*)d_in[5];
    const float* b_fm    = (const float*)d_in[6];
    const float* w_lin1  = (const float*)d_in[7];
    const float* w_lin2  = (const float*)d_in[8];
    float* out = (float*)d_out;
    float* ws  = (float*)d_ws;
    ushort* uiL = (ushort*)(ws + WS_UIT);
    ushort* ufL = (ushort*)(ws + WS_UFT);

    k_prepM<<<40, 256, 0, stream>>>(w_lin1, w_lin2, ws + WS_M);
    k_prepW<<<1, 256, 0, stream>>>(w_conv1, b_conv1, w_conv2, b_conv2, ws);
    k_conv<<<dim3(10, 10, 8), 256, 0, stream>>>(x, ws, ws + WS_INI);
    k_border<<<5104, 256, 0, stream>>>(x, b_conv2, ws, ws + WS_INI);  // 20416 waves
    dim3 gt(16, 16, 2);
    k_trans<0><<<gt, 256, 0, stream>>>(ws + WS_INI, w_fm, b_fm, ws, uiL);
    k_trans<1><<<gt, 256, 0, stream>>>(x, w_fm, b_fm, ws, ufL);
    dim3 ga(8, 8, 16);
    k_att<<<ga, 256, 0, stream>>>(uiL, ufL, out);
}